// Round 14
// baseline (1155.068 us; speedup 1.0000x reference)
//
#include <hip/hip_runtime.h>
#include <hip/hip_bf16.h>
#include <stdint.h>

#define TOKENS 8192
#define DIN    4096
#define DOUT   16384

#define BM 256
#define BN 256
#define BKT 64                 // K per tile
#define NT (DIN / BKT)         // 64 K-tiles
#define NJ (NT / 2)            // 32 iterations, 2 tiles each

typedef short s16x8 __attribute__((ext_vector_type(8)));
typedef float f32x16 __attribute__((ext_vector_type(16)));

#define AS1 __attribute__((address_space(1)))
#define AS3 __attribute__((address_space(3)))
#define VMCNT(n)  asm volatile("s_waitcnt vmcnt(" #n ")" ::: "memory")
#define BAR()     __builtin_amdgcn_s_barrier()

__device__ __forceinline__ unsigned short f2bf(float f) {
  unsigned int u = __float_as_uint(f);
  u += 0x7fffu + ((u >> 16) & 1u);   // round-to-nearest-even
  return (unsigned short)(u >> 16);
}

// -------- Kernel 1: LayerNorm fp32 -> bf16
__global__ __launch_bounds__(256) void ln_kernel(const float* __restrict__ x,
                                                 unsigned short* __restrict__ xn) {
  const int row = blockIdx.x;
  const float4* xr = reinterpret_cast<const float4*>(x + (size_t)row * DIN);
  float4 v[4];
  float sum = 0.f, ssq = 0.f;
#pragma unroll
  for (int i = 0; i < 4; ++i) {
    v[i] = xr[threadIdx.x + i * 256];
    sum += v[i].x + v[i].y + v[i].z + v[i].w;
    ssq += v[i].x * v[i].x + v[i].y * v[i].y + v[i].z * v[i].z + v[i].w * v[i].w;
  }
#pragma unroll
  for (int off = 32; off > 0; off >>= 1) {
    sum += __shfl_xor(sum, off, 64);
    ssq += __shfl_xor(ssq, off, 64);
  }
  __shared__ float red[8];
  const int wid = threadIdx.x >> 6;
  if ((threadIdx.x & 63) == 0) { red[wid] = sum; red[wid + 4] = ssq; }
  __syncthreads();
  sum = red[0] + red[1] + red[2] + red[3];
  ssq = red[4] + red[5] + red[6] + red[7];
  const float mean = sum * (1.f / DIN);
  const float var  = ssq * (1.f / DIN) - mean * mean;
  const float rs   = rsqrtf(var + 1e-5f);
  ushort4* xo = reinterpret_cast<ushort4*>(xn + (size_t)row * DIN);
#pragma unroll
  for (int i = 0; i < 4; ++i) {
    ushort4 o;
    o.x = f2bf((v[i].x - mean) * rs);
    o.y = f2bf((v[i].y - mean) * rs);
    o.z = f2bf((v[i].z - mean) * rs);
    o.w = f2bf((v[i].w - mean) * rs);
    xo[threadIdx.x + i * 256] = o;
  }
}

// -------- Kernel 2: W fp32 -> bf16
__global__ __launch_bounds__(256) void cvt_kernel(const float* __restrict__ W,
                                                  unsigned short* __restrict__ Wb) {
  const size_t i = (size_t)blockIdx.x * 256 + threadIdx.x;
  float4 v = reinterpret_cast<const float4*>(W)[i];
  ushort4 o;
  o.x = f2bf(v.x); o.y = f2bf(v.y); o.z = f2bf(v.z); o.w = f2bf(v.w);
  reinterpret_cast<ushort4*>(Wb)[i] = o;
}

// -------- Kernel 3: 256x256, 32x32x16 MFMA, 4-phase, CROSS-PHASE B-PREFETCH.
// R14 vs R13: B-fragment reads move one phase EARLY into ping-pong register
// sets (bX used ph1/ph2, bY used ph3/ph4), so each prefetch burst overlaps
// the host phase's MFMA cluster (LDS pipe busy during matrix pipe work —
// the overlap R4-R13's in-phase reads never achieved). Enabled by a
// rebalanced stage plan (B-buf's last read is earlier than A-buf's):
//   stages/phase: ph1 A-buf1(t1) | ph2 B-buf0(t2) | ph3 A-buf0(t2) | ph4 B-buf1(t3)
//   vmcnt(4) at EVERY phase top = drains exactly the 2-phase-old batch.
// Ledger (verified): every region confirmed >=1 phase before first read,
// 2-phase (~4000cy >> 900cy HBM) cross-wave latency margin, every stage
// >=1 closing-barrier after the overwritten region's last read.
__global__ __launch_bounds__(512, 2) void gemm_sig(const unsigned short* __restrict__ A,
                                                   const unsigned short* __restrict__ B,
                                                   float* __restrict__ C) {
  __shared__ unsigned short Asl[2 * 256 * 64];  // 64 KB
  __shared__ unsigned short Bsl[2 * 256 * 64];  // 64 KB

  // XCD chunk (nwg=2048, cpx=256) then 2x2 super-tile grouping.
  const int bid = blockIdx.x;
  const int cpx = gridDim.x >> 3;              // 256
  const int swz = (bid & 7) * cpx + (bid >> 3);
  const int grp = swz >> 2;                    // 0..511 = 16 (bm) x 32 (bn)
  const int sub = swz & 3;
  const int bm = ((grp & 15) << 1) | (sub & 1);    // 0..31
  const int bn = ((grp >> 4) << 1) | (sub >> 1);   // 0..63

  const int tid  = threadIdx.x;
  const int wid  = tid >> 6;
  const int lane = tid & 63;
  const int wr = wid >> 2, wc = wid & 3;

  const unsigned short* gA = A + (size_t)bm * BM * DIN;
  const unsigned short* gB = B + (size_t)bn * BN * DIN;

  // Staging: 1 gload = 512 lanes x 16B = 8 KB = 64 rows (one quarter).
  // Lane l of wave wid writes LDS row wid*8+(l>>3), slot l&7 (linear dest);
  // fetches global slot (l&7)^(l>>3) (involution keyed on row&7).
  const int l8 = lane >> 3, l7 = lane & 7;
  const int csw = l7 ^ l8;
  const unsigned short* sA = gA + (size_t)(wid * 8 + l8) * DIN + csw * 8;
  const unsigned short* sB = gB + (size_t)(wid * 8 + l8) * DIN + csw * 8;
  const int dOfs = wid * 512;   // ushort units

#define STG_A(p, kt) do { _Pragma("unroll") for (int q = 0; q < 4; ++q) \
  __builtin_amdgcn_global_load_lds( \
    (const AS1 void*)(sA + (size_t)q * 64 * DIN + (size_t)(kt) * BKT), \
    (AS3 void*)(Asl + ((p) * 256 + q * 64) * 64 + dOfs), 16, 0, 0); } while (0)
#define STG_B(p, kt) do { _Pragma("unroll") for (int q = 0; q < 4; ++q) \
  __builtin_amdgcn_global_load_lds( \
    (const AS1 void*)(sB + (size_t)q * 64 * DIN + (size_t)(kt) * BKT), \
    (AS3 void*)(Bsl + ((p) * 256 + q * 64) * 64 + dOfs), 16, 0, 0); } while (0)

  // Read side (32x32 frags): row = base + (lane&31); logical k-slot for
  // kstep ks = 2*ks + (lane>>5); stored at slot ^ (row&7), row&7 = lane&7.
  const int l31 = lane & 31;
  const int l5  = lane >> 5;
  int aRow[4], bRow[2], kslt[4];
#pragma unroll
  for (int mb = 0; mb < 4; ++mb) aRow[mb] = (wr * 128 + mb * 32 + l31) * 64;
#pragma unroll
  for (int nb = 0; nb < 2; ++nb) bRow[nb] = (wc * 64 + nb * 32 + l31) * 64;
#pragma unroll
  for (int ks = 0; ks < 4; ++ks) kslt[ks] = ((2 * ks + l5) ^ l7) * 8;

  s16x8 a0[4], a1[4], bX[8], bY[8];   // bArr[nb*4+ks]
  f32x16 acc[4][2] = {};

#define RD_AP(p, mp) do { _Pragma("unroll") for (int ks = 0; ks < 4; ++ks) { \
    a0[ks] = *reinterpret_cast<const s16x8*>(Asl + (p) * 16384 + aRow[2 * (mp)] + kslt[ks]); \
    a1[ks] = *reinterpret_cast<const s16x8*>(Asl + (p) * 16384 + aRow[2 * (mp) + 1] + kslt[ks]); } } while (0)
#define RD_BPRE(p, dst) do { _Pragma("unroll") for (int ks = 0; ks < 4; ++ks) { \
    dst[ks]     = *reinterpret_cast<const s16x8*>(Bsl + (p) * 16384 + bRow[0] + kslt[ks]); \
    dst[4 + ks] = *reinterpret_cast<const s16x8*>(Bsl + (p) * 16384 + bRow[1] + kslt[ks]); } } while (0)
#define MMPH(mp, bArr) do { _Pragma("unroll") for (int ks = 0; ks < 4; ++ks) { \
    acc[2 * (mp)][0]     = __builtin_amdgcn_mfma_f32_32x32x16_bf16(a0[ks], bArr[ks],     acc[2 * (mp)][0], 0, 0, 0); \
    acc[2 * (mp)][1]     = __builtin_amdgcn_mfma_f32_32x32x16_bf16(a0[ks], bArr[4 + ks], acc[2 * (mp)][1], 0, 0, 0); \
    acc[2 * (mp) + 1][0] = __builtin_amdgcn_mfma_f32_32x32x16_bf16(a1[ks], bArr[ks],     acc[2 * (mp) + 1][0], 0, 0, 0); \
    acc[2 * (mp) + 1][1] = __builtin_amdgcn_mfma_f32_32x32x16_bf16(a1[ks], bArr[4 + ks], acc[2 * (mp) + 1][1], 0, 0, 0); } } while (0)

  // Prologue ("iter -1 ph2..ph4"): B-buf0(t0), A-buf0(t0), B-buf1(t1).
  // vmcnt(4)+BAR publishes buf0 (vmcnt BEFORE barrier => cross-wave safe),
  // then prefetch bX from B-buf0.
  STG_B(0, 0); STG_A(0, 0); STG_B(1, 1);
  VMCNT(4); BAR();
  RD_BPRE(0, bX);

  for (int j = 0; j < NJ - 1; ++j) {
    const int t1 = 2 * j + 1, t2 = 2 * j + 2, t3 = 2 * j + 3;
    // ph1: A-mpair0(buf0) reads; MFMA x bX; stage A-buf1(t1)
    VMCNT(4);
    RD_AP(0, 0);
    STG_A(1, t1);
    MMPH(0, bX); BAR();
    // ph2: A-mpair1(buf0); prefetch bY <- B-buf1(t1); MFMA x bX; stage B-buf0(t2)
    VMCNT(4);
    RD_AP(0, 1); RD_BPRE(1, bY);
    STG_B(0, t2);
    MMPH(1, bX); BAR();
    // ph3: A-mpair0(buf1); MFMA x bY; stage A-buf0(t2)
    VMCNT(4);
    RD_AP(1, 0);
    STG_A(0, t2);
    MMPH(0, bY); BAR();
    // ph4: A-mpair1(buf1); prefetch bX <- B-buf0(t2, next iter); MFMA x bY; stage B-buf1(t3)
    VMCNT(4);
    RD_AP(1, 1); RD_BPRE(0, bX);
    STG_B(1, t3);
    MMPH(1, bY); BAR();
  }

  // Tail iter (t0 = NT-2, t1 = NT-1): only A-buf1 stage; exact drains.
  {
    const int t1 = NT - 1;
    VMCNT(4);                    // drains A-buf0 stage (ph3 prev)
    RD_AP(0, 0);
    STG_A(1, t1);
    MMPH(0, bX); BAR();
    VMCNT(4);                    // drains B-buf1 stage (ph4 prev)
    RD_AP(0, 1); RD_BPRE(1, bY);
    MMPH(1, bX); BAR();
    VMCNT(0);                    // drains A-buf1 stage (ph1 this iter)
    RD_AP(1, 0);
    MMPH(0, bY); BAR();
    RD_AP(1, 1);
    MMPH(1, bY); BAR();
  }

#undef STG_A
#undef STG_B
#undef RD_AP
#undef RD_BPRE
#undef MMPH

  // Epilogue: 32x32 C/D layout: col = lane&31,
  // row = (reg&3) + 8*(reg>>2) + 4*(lane>>5).
  const int crow0 = bm * BM + wr * 128 + 4 * l5;
  const int ccol0 = bn * BN + wc * 64 + l31;
#pragma unroll
  for (int mb = 0; mb < 4; ++mb)
#pragma unroll
    for (int nb = 0; nb < 2; ++nb)
#pragma unroll
      for (int reg = 0; reg < 16; ++reg) {
        const int r = crow0 + mb * 32 + (reg & 3) + 8 * (reg >> 2);
        const int c = ccol0 + nb * 32;
        const float v = acc[mb][nb][reg];
        C[(size_t)r * DOUT + c] = 1.f / (1.f + __expf(-v));
      }
}

extern "C" void kernel_launch(void* const* d_in, const int* in_sizes, int n_in,
                              void* d_out, int out_size, void* d_ws, size_t ws_size,
                              hipStream_t stream) {
  const float* x = (const float*)d_in[0];
  const float* W = (const float*)d_in[1];
  float* out = (float*)d_out;

  unsigned short* xn = (unsigned short*)d_ws;                    // 64 MiB
  unsigned short* Wb = xn + (size_t)TOKENS * DIN;                // 128 MiB

  ln_kernel<<<TOKENS, 256, 0, stream>>>(x, xn);
  cvt_kernel<<<((size_t)DOUT * DIN) / 1024, 256, 0, stream>>>(W, Wb);
  gemm_sig<<<(TOKENS / BM) * (DOUT / BN), 512, 0, stream>>>(xn, Wb, out);
}